// Round 21
// baseline (222.847 us; speedup 1.0000x reference)
//
#include <hip/hip_runtime.h>
#include <math.h>

#define BB 8
#define HH 64
#define WW 64
#define CIN 192
#define INNER 384
#define LL 4096          // HH*WW
#define NSTATE 32
#define PDIM 64
#define NHK 6            // INNER/PDIM
#define NHEADS 12        // 2*NHK
#define HID 768
#define CPROJ 70         // 2*NSTATE + NHK
#define QC 64            // chunk length
#define NC 64            // LL/QC chunks

// workspace layout (bytes)
#define WS_XLZ   0u                   // bf16 xlz (B,L,768) 50331648 ; h1_bf overlay after out_proj
#define WS_XC    50331648u            // bf16 xc (B,L,384) 25165824
#define WS_Y1    75497472u            // bf16 y1 (B,L,384) 25165824
#define WS_BCBF  100663296u           // bf16 BCbf (B,L,2,64) 8388608 ; out_bf overlay after intra
#define WS_DTRAW 109051904u           // f32 dtraw (B,L,2,6) 1572864 (live until intra)
#define WS_CUME  119013376u           // f32 cumend (B,NH,NC) 24576
#define WS_SHB   122159104u           // bf16 SH (B,NH,NC,P,N) 25165824
#define WS_Y0    147324928u           // bf16 y0 (B,L,384) 25165824
#define WS_XBF   172490752u           // bf16 x_bf (M,192) 12582912 (dead after in_proj)
#define WS_WINB  185073664u           // W_in bf16 768x192      294912
#define WS_WPADB 185368576u           // xpw padded bf16 2x128x384 196608
#define WS_WOUTB 185565184u           // W_out padded bf16 256x384 196608
#define WS_W1B   185761792u           // W1 bf16 768x192        294912
#define WS_W2B   186056704u           // W2 padded bf16 256x768 393216
#define WS_REQ   186449920u

typedef __attribute__((ext_vector_type(8))) short short8;
typedef __attribute__((ext_vector_type(4))) float f32x4;

__device__ __forceinline__ float silu_f(float x) { return x / (1.f + __expf(-x)); }

__device__ __forceinline__ unsigned short f2bf(float f) {
    unsigned u = __float_as_uint(f);
    u += 0x7fffu + ((u >> 16) & 1u);
    return (unsigned short)(u >> 16);
}
__device__ __forceinline__ float bf2f(unsigned short u) {
    return __uint_as_float(((unsigned)u) << 16);
}

// ---------------------------------------------------------------------------
// A-fragment loader.  AMODE 0: bf16.  2: gated (y0+y1)*silu(z).
// ---------------------------------------------------------------------------
template<int AMODE>
__device__ __forceinline__ short8 load_a(const void* A, const unsigned short* Ay0,
                                         const unsigned short* Ay1, const unsigned short* Az,
                                         int row, int col, int Kd)
{
    if constexpr (AMODE == 0) {
        return *(const short8*)((const unsigned short*)A + (size_t)row * Kd + col);
    } else {
        const size_t yo = (size_t)row * INNER + col;
        const uint4 a  = *(const uint4*)(Ay0 + yo);
        const uint4 bv = *(const uint4*)(Ay1 + yo);
        const uint4 zv = *(const uint4*)(Az + (size_t)row * 768 + INNER + col);
        const unsigned ua[4]={a.x,a.y,a.z,a.w}, ub[4]={bv.x,bv.y,bv.z,bv.w}, uz[4]={zv.x,zv.y,zv.z,zv.w};
        short8 r;
        #pragma unroll
        for (int w2 = 0; w2 < 4; ++w2) {
            const float ylo = __uint_as_float(ua[w2] << 16) + __uint_as_float(ub[w2] << 16);
            const float yhi = __uint_as_float(ua[w2] & 0xffff0000u) + __uint_as_float(ub[w2] & 0xffff0000u);
            const float zlo = __uint_as_float(uz[w2] << 16);
            const float zhi = __uint_as_float(uz[w2] & 0xffff0000u);
            r[2*w2+0] = (short)f2bf(ylo * silu_f(zlo));
            r[2*w2+1] = (short)f2bf(yhi * silu_f(zhi));
        }
        return r;
    }
}

// ---------------------------------------------------------------------------
// bf16 MFMA GEMM: C[m,n] = sum_k A[m,k]*Wt[n,k].  128x128 tile, BK=64.
// EPI: 0 Cf=acc; 1 Cb=bf16(silu(acc+bias)); 2 Cf=acc+bias+res; 3 Cf=acc+res & Cb;
//      4 Cb=bf16(acc).
// ---------------------------------------------------------------------------
template<int EPI, int TRANSA, int AMODE>
__global__ __launch_bounds__(256)
void gemm_bf16(const void* __restrict__ A, const unsigned short* __restrict__ Wt,
               const float* __restrict__ bias, const float* __restrict__ res,
               float* __restrict__ Cf, unsigned short* __restrict__ Cb,
               const unsigned short* __restrict__ Ay0, const unsigned short* __restrict__ Ay1,
               const unsigned short* __restrict__ Az,
               int Kd, int ldc, int nmax)
{
    __shared__ __align__(16) short Als[128 * 64];
    __shared__ __align__(16) short Bls[128 * 64];
    const int tid = threadIdx.x;
    const int m0 = blockIdx.x * 128;
    const int n0 = blockIdx.y * 128;
    const int lane = tid & 63;
    const int wv = tid >> 6;
    const int wm = (wv >> 1) << 6;
    const int wn = (wv & 1) << 6;

    int am[4], ac[4];
    const unsigned short* gB[4];
    int lw[4];
    #pragma unroll
    for (int c = 0; c < 4; ++c) {
        const int idx = c * 256 + tid;
        const int row = idx >> 3;
        const int kb  = idx & 7;
        const int sb  = kb ^ (row & 7);
        lw[c] = row * 64 + sb * 8;
        int arow;
        const int mm = m0 + row;
        if (TRANSA) {
            const int bq = mm >> 12, lq = mm & 4095;
            arow = (bq << 12) + (((lq & 63) << 6) + (lq >> 6));
        } else {
            arow = mm;
        }
        am[c] = arow;
        ac[c] = kb * 8;
        gB[c] = Wt + (size_t)(n0 + row) * Kd + kb * 8;
    }

    f32x4 acc[4][4];
    #pragma unroll
    for (int i = 0; i < 4; ++i)
        #pragma unroll
        for (int j = 0; j < 4; ++j) acc[i][j] = (f32x4){0.f, 0.f, 0.f, 0.f};

    const int NT = Kd >> 6;
    short8 pA[4], pB[4];
    #pragma unroll
    for (int c = 0; c < 4; ++c) {
        pA[c] = load_a<AMODE>(A, Ay0, Ay1, Az, am[c], ac[c], Kd);
        pB[c] = *(const short8*)(gB[c]);
    }
    for (int kt = 0; kt < NT; ++kt) {
        __syncthreads();
        #pragma unroll
        for (int c = 0; c < 4; ++c) {
            *(short8*)&Als[lw[c]] = pA[c];
            *(short8*)&Bls[lw[c]] = pB[c];
        }
        __syncthreads();
        if (kt + 1 < NT) {
            #pragma unroll
            for (int c = 0; c < 4; ++c) {
                pA[c] = load_a<AMODE>(A, Ay0, Ay1, Az, am[c], ac[c] + (kt + 1) * 64, Kd);
                pB[c] = *(const short8*)(gB[c] + (kt + 1) * 64);
            }
        }
        #pragma unroll
        for (int ks = 0; ks < 2; ++ks) {
            short8 af[4], bfr[4];
            #pragma unroll
            for (int r = 0; r < 4; ++r) {
                const int rowa = wm + r * 16 + (lane & 15);
                const int rowb = wn + r * 16 + (lane & 15);
                const int kb = ks * 4 + (lane >> 4);
                af[r]  = *(const short8*)&Als[rowa * 64 + ((kb ^ (rowa & 7)) << 3)];
                bfr[r] = *(const short8*)&Bls[rowb * 64 + ((kb ^ (rowb & 7)) << 3)];
            }
            #pragma unroll
            for (int mr = 0; mr < 4; ++mr)
                #pragma unroll
                for (int nr = 0; nr < 4; ++nr)
                    acc[mr][nr] = __builtin_amdgcn_mfma_f32_16x16x32_bf16(af[mr], bfr[nr], acc[mr][nr], 0, 0, 0);
        }
    }
    #pragma unroll
    for (int mr = 0; mr < 4; ++mr) {
        #pragma unroll
        for (int nr = 0; nr < 4; ++nr) {
            const int n = n0 + wn + nr * 16 + (lane & 15);
            if (n >= nmax) continue;
            const int mb = m0 + wm + mr * 16 + ((lane >> 4) << 2);
            #pragma unroll
            for (int q = 0; q < 4; ++q) {
                const size_t off = (size_t)(mb + q) * ldc + n;
                float v = acc[mr][nr][q];
                if (EPI == 0) { Cf[off] = v; }
                else if (EPI == 1) { v = silu_f(v + bias[n]); Cb[off] = f2bf(v); }
                else if (EPI == 2) { v += bias[n] + res[off]; Cf[off] = v; }
                else if (EPI == 3) { v += res[off]; Cf[off] = v; Cb[off] = f2bf(v); }
                else if (EPI == 4) { Cb[off] = f2bf(v); }
            }
        }
    }
}

// ---------------------------------------------------------------------------
// Merged BCdt projection: both scan directions in one dispatch.
// grid (M/128, 2); blockIdx.y = k.
// ---------------------------------------------------------------------------
__global__ __launch_bounds__(256)
void gemm_bcdt(const unsigned short* __restrict__ A, const unsigned short* __restrict__ wpadb,
               float* __restrict__ dtraw, unsigned short* __restrict__ BCbf)
{
    __shared__ __align__(16) short Als[128 * 64];
    __shared__ __align__(16) short Bls[128 * 64];
    const int tid = threadIdx.x;
    const int m0 = blockIdx.x * 128;
    const int kk = blockIdx.y;
    const int lane = tid & 63;
    const int wv = tid >> 6;
    const int wm = (wv >> 1) << 6;
    const int wn = (wv & 1) << 6;
    const int Kd = INNER;
    const unsigned short* Wt = wpadb + (size_t)kk * 128 * INNER;

    int am[4], ac[4];
    const unsigned short* gB[4];
    int lw[4];
    #pragma unroll
    for (int c = 0; c < 4; ++c) {
        const int idx = c * 256 + tid;
        const int row = idx >> 3;
        const int kb  = idx & 7;
        const int sb  = kb ^ (row & 7);
        lw[c] = row * 64 + sb * 8;
        const int mm = m0 + row;
        int arow;
        if (kk) {
            const int bq = mm >> 12, lq = mm & 4095;
            arow = (bq << 12) + (((lq & 63) << 6) + (lq >> 6));
        } else {
            arow = mm;
        }
        am[c] = arow;
        ac[c] = kb * 8;
        gB[c] = Wt + (size_t)row * Kd + kb * 8;
    }

    f32x4 acc[4][4];
    #pragma unroll
    for (int i = 0; i < 4; ++i)
        #pragma unroll
        for (int j = 0; j < 4; ++j) acc[i][j] = (f32x4){0.f, 0.f, 0.f, 0.f};

    short8 pA[4], pB[4];
    #pragma unroll
    for (int c = 0; c < 4; ++c) {
        pA[c] = *(const short8*)(A + (size_t)am[c] * Kd + ac[c]);
        pB[c] = *(const short8*)(gB[c]);
    }
    for (int kt = 0; kt < 6; ++kt) {
        __syncthreads();
        #pragma unroll
        for (int c = 0; c < 4; ++c) {
            *(short8*)&Als[lw[c]] = pA[c];
            *(short8*)&Bls[lw[c]] = pB[c];
        }
        __syncthreads();
        if (kt + 1 < 6) {
            #pragma unroll
            for (int c = 0; c < 4; ++c) {
                pA[c] = *(const short8*)(A + (size_t)am[c] * Kd + ac[c] + (kt + 1) * 64);
                pB[c] = *(const short8*)(gB[c] + (kt + 1) * 64);
            }
        }
        #pragma unroll
        for (int ks = 0; ks < 2; ++ks) {
            short8 af[4], bfr[4];
            #pragma unroll
            for (int r = 0; r < 4; ++r) {
                const int rowa = wm + r * 16 + (lane & 15);
                const int rowb = wn + r * 16 + (lane & 15);
                const int kb = ks * 4 + (lane >> 4);
                af[r]  = *(const short8*)&Als[rowa * 64 + ((kb ^ (rowa & 7)) << 3)];
                bfr[r] = *(const short8*)&Bls[rowb * 64 + ((kb ^ (rowb & 7)) << 3)];
            }
            #pragma unroll
            for (int mr = 0; mr < 4; ++mr)
                #pragma unroll
                for (int nr = 0; nr < 4; ++nr)
                    acc[mr][nr] = __builtin_amdgcn_mfma_f32_16x16x32_bf16(af[mr], bfr[nr], acc[mr][nr], 0, 0, 0);
        }
    }
    float* Cf = dtraw + 6 * kk;
    unsigned short* Cb = BCbf + 64 * kk;
    #pragma unroll
    for (int mr = 0; mr < 4; ++mr) {
        #pragma unroll
        for (int nr = 0; nr < 4; ++nr) {
            const int n = wn + nr * 16 + (lane & 15);
            if (n >= CPROJ) continue;
            const int mb = m0 + wm + mr * 16 + ((lane >> 4) << 2);
            #pragma unroll
            for (int q = 0; q < 4; ++q) {
                const float v = acc[mr][nr][q];
                if (n < 64) Cb[(size_t)(mb + q) * 128 + n] = f2bf(v);
                else        Cf[(size_t)(mb + q) * 12 + (n - 64)] = v;
            }
        }
    }
}

// ---------------------------------------------------------------------------
// All conversions in one launch: x (6291456) then weights (688128).
// ---------------------------------------------------------------------------
__global__ __launch_bounds__(256)
void cvt_all_kernel(const float* __restrict__ x, const float* __restrict__ W_in,
                    const float* __restrict__ W1, const float* __restrict__ xpw,
                    const float* __restrict__ W_out, const float* __restrict__ W2,
                    unsigned short* __restrict__ x_bf,
                    unsigned short* __restrict__ Winb, unsigned short* __restrict__ W1b,
                    unsigned short* __restrict__ wpadb, unsigned short* __restrict__ Woutb,
                    unsigned short* __restrict__ W2b)
{
    int i = blockIdx.x * 256 + threadIdx.x;
    if (i < 6291456) { x_bf[i] = f2bf(x[i]); return; }
    i -= 6291456;
    if (i < 147456) { Winb[i] = f2bf(W_in[i]); return; }
    i -= 147456;
    if (i < 147456) { W1b[i] = f2bf(W1[i]); return; }
    i -= 147456;
    if (i < 98304) {
        const int d = i % 384;
        const int rr = (i / 384) & 127;
        const int k = i / 49152;
        wpadb[i] = (rr < CPROJ) ? f2bf(xpw[((size_t)k * CPROJ + rr) * 384 + d]) : (unsigned short)0;
        return;
    }
    i -= 98304;
    if (i < 98304) {
        const int rr = i / 384;
        Woutb[i] = (rr < CIN) ? f2bf(W_out[i]) : (unsigned short)0;
        return;
    }
    i -= 98304;
    if (i < 196608) {
        const int rr = i / 768;
        W2b[i] = (rr < CIN) ? f2bf(W2[i]) : (unsigned short)0;
    }
}

// ---------------------------------------------------------------------------
// Depthwise 3x3 conv + bias + SiLU, rolling-row (8 rows/thread, 8 ch/thread).
// ---------------------------------------------------------------------------
__global__ __launch_bounds__(256)
void conv_dw_kernel(const unsigned short* __restrict__ xlz, const float* __restrict__ cw,
                    const float* __restrict__ cb, unsigned short* __restrict__ xcbf)
{
    const int t = blockIdx.x * 256 + threadIdx.x;   // < 196608
    const int dv = t % 48;
    int r = t / 48;
    const int j  = r & 63;  r >>= 6;
    const int ib = r & 7;   r >>= 3;
    const int b  = r;
    const int d0 = dv * 8;
    const int i0 = ib * 8;

    float wreg[72];
    {
        const float4* w4 = (const float4*)(cw + d0 * 9);
        #pragma unroll
        for (int u = 0; u < 18; ++u) {
            const float4 v = w4[u];
            wreg[4*u+0]=v.x; wreg[4*u+1]=v.y; wreg[4*u+2]=v.z; wreg[4*u+3]=v.w;
        }
    }
    float bias[8];
    {
        const float4 b0 = *(const float4*)(cb + d0);
        const float4 b1 = *(const float4*)(cb + d0 + 4);
        bias[0]=b0.x; bias[1]=b0.y; bias[2]=b0.z; bias[3]=b0.w;
        bias[4]=b1.x; bias[5]=b1.y; bias[6]=b1.z; bias[7]=b1.w;
    }

    const unsigned short* base = xlz + ((size_t)b << 12) * 768 + d0;
    const int jok[3] = { (j - 1 >= 0), 1, (j + 1 < WW) };

    unsigned rm[3][4], r0[3][4], rp[3][4];
    #pragma unroll
    for (int cj = 0; cj < 3; ++cj) {
        uint4 vm = make_uint4(0,0,0,0), v0 = make_uint4(0,0,0,0);
        if (jok[cj]) {
            if (i0 - 1 >= 0) vm = *(const uint4*)(base + (size_t)((i0-1) * 64 + j - 1 + cj) * 768);
            v0 = *(const uint4*)(base + (size_t)(i0 * 64 + j - 1 + cj) * 768);
        }
        rm[cj][0]=vm.x; rm[cj][1]=vm.y; rm[cj][2]=vm.z; rm[cj][3]=vm.w;
        r0[cj][0]=v0.x; r0[cj][1]=v0.y; r0[cj][2]=v0.z; r0[cj][3]=v0.w;
    }

    #pragma unroll
    for (int ii = 0; ii < 8; ++ii) {
        const int i = i0 + ii;
        #pragma unroll
        for (int cj = 0; cj < 3; ++cj) {
            uint4 vp = make_uint4(0,0,0,0);
            if (jok[cj] && (i + 1 < HH))
                vp = *(const uint4*)(base + (size_t)((i+1) * 64 + j - 1 + cj) * 768);
            rp[cj][0]=vp.x; rp[cj][1]=vp.y; rp[cj][2]=vp.z; rp[cj][3]=vp.w;
        }
        float acc[8];
        #pragma unroll
        for (int ch = 0; ch < 8; ++ch) acc[ch] = bias[ch];
        #pragma unroll
        for (int cj = 0; cj < 3; ++cj) {
            #pragma unroll
            for (int w2 = 0; w2 < 4; ++w2) {
                acc[2*w2+0] = fmaf(__uint_as_float(rm[cj][w2] << 16),        wreg[(2*w2+0)*9 + cj],     acc[2*w2+0]);
                acc[2*w2+1] = fmaf(__uint_as_float(rm[cj][w2] & 0xffff0000u), wreg[(2*w2+1)*9 + cj],     acc[2*w2+1]);
                acc[2*w2+0] = fmaf(__uint_as_float(r0[cj][w2] << 16),        wreg[(2*w2+0)*9 + 3 + cj], acc[2*w2+0]);
                acc[2*w2+1] = fmaf(__uint_as_float(r0[cj][w2] & 0xffff0000u), wreg[(2*w2+1)*9 + 3 + cj], acc[2*w2+1]);
                acc[2*w2+0] = fmaf(__uint_as_float(rp[cj][w2] << 16),        wreg[(2*w2+0)*9 + 6 + cj], acc[2*w2+0]);
                acc[2*w2+1] = fmaf(__uint_as_float(rp[cj][w2] & 0xffff0000u), wreg[(2*w2+1)*9 + 6 + cj], acc[2*w2+1]);
            }
        }
        unsigned o[4];
        #pragma unroll
        for (int w2 = 0; w2 < 4; ++w2) {
            const unsigned lo = f2bf(silu_f(acc[2*w2+0]));
            const unsigned hi = f2bf(silu_f(acc[2*w2+1]));
            o[w2] = lo | (hi << 16);
        }
        *(uint4*)(xcbf + ((size_t)(b << 12) + (size_t)(i * 64 + j)) * INNER + d0) =
            make_uint4(o[0], o[1], o[2], o[3]);
        #pragma unroll
        for (int cj = 0; cj < 3; ++cj)
            #pragma unroll
            for (int w2 = 0; w2 < 4; ++w2) {
                rm[cj][w2] = r0[cj][w2];
                r0[cj][w2] = rp[cj][w2];
            }
    }
}

// ---------------------------------------------------------------------------
// In-block dt prefix: wave 0 (tid<64) computes softplus + inclusive prefix of
// dtA for its (b,h,chunk).  Returns via cuS/dtS LDS arrays.
// ---------------------------------------------------------------------------
__device__ __forceinline__ void dt_prefix(const float* __restrict__ dtraw,
                                          const float* __restrict__ dt_bias,
                                          const float* __restrict__ A_logs,
                                          int b, int h, int c, int k, int hq, int tid,
                                          float* cuS, float* dtS)
{
    if (tid < QC) {
        const float dtr = dtraw[(((size_t)b * LL + c * QC + tid) * 2 + k) * 6 + hq];
        const float xx = dtr + dt_bias[h];
        const float sp = (xx > 20.f) ? xx : log1pf(expf(xx));
        float s = -expf(A_logs[h]) * sp;
        #pragma unroll
        for (int d = 1; d < 64; d <<= 1) {
            const float o = __shfl_up(s, d);
            if (tid >= d) s += o;
        }
        cuS[tid] = s;
        dtS[tid] = sp;
    }
}

// ---------------------------------------------------------------------------
// Chunk states via bf16 MFMA: S_c[p,n] = sum_m (rs[m]*x[m][p]) * B[m][n]
// Computes dt prefix in-block; writes chunk-end cum to cumend.
// ---------------------------------------------------------------------------
__global__ __launch_bounds__(256)
void chunk_state_kernel(const unsigned short* __restrict__ xcbf, const unsigned short* __restrict__ BCbf,
                        const float* __restrict__ dtraw, const float* __restrict__ dt_bias,
                        const float* __restrict__ A_logs, float* __restrict__ cumend,
                        unsigned short* __restrict__ SHb)
{
    __shared__ __align__(16) unsigned short Xb[PDIM][72];    // [p][m^]  (X^T, swizzled blocks)
    __shared__ __align__(16) unsigned short Bsc[NSTATE][72]; // [n][m^]  (rs[m]*B^T, swizzled)
    __shared__ float cuS[QC], dtS[QC], rs[QC];
    const int c = blockIdx.x, h = blockIdx.y, b = blockIdx.z;
    const int k = h / NHK;
    const int hq = h - k * NHK;
    const int dch0 = hq * PDIM;
    const int tid = threadIdx.x;
    const int lane = tid & 63;
    const int w = tid >> 6;

    #pragma unroll
    for (int r2 = 0; r2 < 2; ++r2) {
        const int idx = tid + r2 * 256;
        const int m = idx >> 3, pg = idx & 7;
        const int pos = (k == 0) ? (c * QC + m) : (m * QC + c);
        const uint4 v = *(const uint4*)(xcbf + (((size_t)b << 12) + pos) * INNER + dch0 + pg * 8);
        const unsigned ua[4] = {v.x, v.y, v.z, v.w};
        const int mcol = (((m >> 3) ^ pg) << 3) + (m & 7);   // (p>>3)&7 == pg
        #pragma unroll
        for (int e2 = 0; e2 < 4; ++e2) {
            Xb[pg * 8 + 2*e2 + 0][mcol] = (unsigned short)(ua[e2] & 0xffffu);
            Xb[pg * 8 + 2*e2 + 1][mcol] = (unsigned short)(ua[e2] >> 16);
        }
    }
    dt_prefix(dtraw, dt_bias, A_logs, b, h, c, k, hq, tid, cuS, dtS);
    if (tid == QC - 1)
        cumend[((size_t)b * NHEADS + h) * NC + c] = cuS[QC - 1];
    __syncthreads();
    if (tid < QC)
        rs[tid] = dtS[tid] * __expf(cuS[QC-1] - cuS[tid]);
    __syncthreads();
    #pragma unroll
    for (int r = 0; r < 8; ++r) {
        const int idx = tid + r * 256;
        const int m = idx >> 5, n = idx & 31;
        Bsc[n][(((m >> 3) ^ (n >> 3)) << 3) + (m & 7)] =
            f2bf(rs[m] * bf2f(BCbf[(((size_t)b * LL + c * QC + m) * 2 + k) * 64 + n]));
    }
    __syncthreads();

    const int rowf = lane & 15;
    const int ko   = lane >> 4;
    const int xsw = (w * 2 + (rowf >> 3)) & 7;   // (row>>3)&7 for row = w*16+rowf
    f32x4 acc[2] = {{0.f,0.f,0.f,0.f},{0.f,0.f,0.f,0.f}};
    #pragma unroll
    for (int ks = 0; ks < 2; ++ks) {
        const short8 af = *(const short8*)&Xb[w * 16 + rowf][((ks * 4 + ko) ^ xsw) << 3];
        #pragma unroll
        for (int nt = 0; nt < 2; ++nt) {
            const int bsw = (nt * 2 + (rowf >> 3)) & 7;
            const short8 bfr = *(const short8*)&Bsc[nt * 16 + rowf][((ks * 4 + ko) ^ bsw) << 3];
            acc[nt] = __builtin_amdgcn_mfma_f32_16x16x32_bf16(af, bfr, acc[nt], 0, 0, 0);
        }
    }
    unsigned short* base = SHb + ((((size_t)b * NHEADS + h) * NC + c) * PDIM) * NSTATE;
    #pragma unroll
    for (int nt = 0; nt < 2; ++nt) {
        #pragma unroll
        for (int q = 0; q < 4; ++q) {
            const int p = w * 16 + ko * 4 + q;
            base[p * NSTATE + nt * 16 + rowf] = f2bf(acc[nt][q]);
        }
    }
}

// ---------------------------------------------------------------------------
// Sequential scan over chunks (in place, bf16 slots, f32 running state).
// 768 blocks x 64 threads, 4 elems (8B)/thread; next-slot prefetch breaks
// the global-load latency chain.  Decays from compact cumend.
// ---------------------------------------------------------------------------
__global__ __launch_bounds__(64)
void state_scan_kernel(unsigned short* __restrict__ SHb, const float* __restrict__ cumend,
                       const float* __restrict__ init_states)
{
    __shared__ float decays[NC];
    const int g = blockIdx.x;
    const int bh = g >> 3;
    const int oct = g & 7;
    const int b = bh / NHEADS;
    const int h = bh % NHEADS;
    const int tid = threadIdx.x;
    decays[tid] = __expf(cumend[((size_t)b * NHEADS + h) * NC + tid]);
    __syncthreads();
    const int p  = oct * 8 + (tid >> 3);
    const int nb = (tid & 7) * 4;
    float hs[4];
    {
        const float* is = init_states + ((size_t)h * PDIM + p) * NSTATE + nb;
        hs[0]=is[0]; hs[1]=is[1]; hs[2]=is[2]; hs[3]=is[3];
    }
    unsigned short* base = SHb + (((size_t)b * NHEADS + h) * NC) * (PDIM * NSTATE) + p * NSTATE + nb;
    uint2 sv = *(const uint2*)base;
    for (int c = 0; c < NC; ++c) {
        unsigned short* slot = base + (size_t)c * (PDIM * NSTATE);
        uint2 nx = make_uint2(0u, 0u);
        if (c + 1 < NC) nx = *(const uint2*)(slot + PDIM * NSTATE);
        const unsigned o0 = (unsigned)f2bf(hs[0]) | ((unsigned)f2bf(hs[1]) << 16);
        const unsigned o1 = (unsigned)f2bf(hs[2]) | ((unsigned)f2bf(hs[3]) << 16);
        *(uint2*)slot = make_uint2(o0, o1);
        const float dc = decays[c];
        hs[0] = fmaf(dc, hs[0], __uint_as_float(sv.x << 16));
        hs[1] = fmaf(dc, hs[1], __uint_as_float(sv.x & 0xffff0000u));
        hs[2] = fmaf(dc, hs[2], __uint_as_float(sv.y << 16));
        hs[3] = fmaf(dc, hs[3], __uint_as_float(sv.y & 0xffff0000u));
        sv = nx;
    }
}

// ---------------------------------------------------------------------------
// Intra-chunk + inter-chunk + D term via bf16 MFMA.  grid (NC, NHEADS, BB).
// Computes dt prefix in-block (wave 0) while other waves stage tiles.
// ---------------------------------------------------------------------------
__global__ __launch_bounds__(256)
void intra_kernel(const unsigned short* __restrict__ xcbf, const unsigned short* __restrict__ BCbf,
                  const float* __restrict__ dtraw, const float* __restrict__ dt_bias,
                  const float* __restrict__ A_logs,
                  const unsigned short* __restrict__ SHb, const float* __restrict__ Ds,
                  unsigned short* __restrict__ y0, unsigned short* __restrict__ y1)
{
    __shared__ __align__(16) unsigned short Bs[QC][40];    // [m][n]
    __shared__ __align__(16) unsigned short Cs[QC][40];    // [i][n]
    __shared__ __align__(16) unsigned short Hs[PDIM][40];  // [p][n]
    __shared__ __align__(16) unsigned short Xb[PDIM][72];  // [p][m^]  (X^T, swizzled)
    __shared__ __align__(16) unsigned short Gb[QC][72];    // [i][m]
    __shared__ float cuS[QC], dtS[QC], Ei[QC];
    const int c = blockIdx.x, h = blockIdx.y, b = blockIdx.z;
    const int k = h / NHK;
    const int hq = h - k * NHK;
    const int dch0 = hq * PDIM;
    const int tid = threadIdx.x;
    const int lane = tid & 63;
    const int w = tid >> 6;

    dt_prefix(dtraw, dt_bias, A_logs, b, h, c, k, hq, tid, cuS, dtS);
    if (tid < QC) Ei[tid] = __expf(cuS[tid]);

    #pragma unroll
    for (int r2 = 0; r2 < 2; ++r2) {
        const int idx = tid + r2 * 256;
        const int m = idx >> 3, pg = idx & 7;
        const int pos = (k == 0) ? (c * QC + m) : (m * QC + c);
        const uint4 v = *(const uint4*)(xcbf + (((size_t)b << 12) + pos) * INNER + dch0 + pg * 8);
        const unsigned ua[4] = {v.x, v.y, v.z, v.w};
        const int mcol = (((m >> 3) ^ pg) << 3) + (m & 7);
        #pragma unroll
        for (int e2 = 0; e2 < 4; ++e2) {
            Xb[pg * 8 + 2*e2 + 0][mcol] = (unsigned short)(ua[e2] & 0xffffu);
            Xb[pg * 8 + 2*e2 + 1][mcol] = (unsigned short)(ua[e2] >> 16);
        }
    }
    // B/C: vector copy from BCbf (b,l,2,64)
    #pragma unroll
    for (int r = 0; r < 2; ++r) {
        const int idx = tid + r * 256;
        const int i = idx >> 3, ch = idx & 7;
        const uint4 v = *(const uint4*)(BCbf + (((size_t)b * LL + c * QC + i) * 2 + k) * 64 + ch * 8);
        if (ch < 4) *(uint4*)&Bs[i][ch * 8] = v;
        else        *(uint4*)&Cs[i][(ch - 4) * 8] = v;
    }
    // H: vector copy
    {
        const int p = tid >> 2, ch = tid & 3;
        *(uint4*)&Hs[p][ch * 8] =
            *(const uint4*)(SHb + ((((size_t)b * NHEADS + h) * NC + c) * PDIM + p) * NSTATE + ch * 8);
    }
    __syncthreads();

    const int rowf = lane & 15;
    const int ko   = lane >> 4;
    const short8 cfrag = *(const short8*)&Cs[w * 16 + rowf][ko * 8];

    // matmul1: G_raw tiles (it=w, mt=0..3)
    f32x4 graw[4];
    #pragma unroll
    for (int mt = 0; mt < 4; ++mt) {
        const short8 bfrag = *(const short8*)&Bs[mt * 16 + rowf][ko * 8];
        graw[mt] = __builtin_amdgcn_mfma_f32_16x16x32_bf16(cfrag, bfrag, (f32x4){0.f,0.f,0.f,0.f}, 0, 0, 0);
    }
    #pragma unroll
    for (int mt = 0; mt < 4; ++mt) {
        const int m = mt * 16 + rowf;
        const float cum = cuS[m];
        const float dtm = dtS[m];
        #pragma unroll
        for (int q = 0; q < 4; ++q) {
            const int i = w * 16 + ko * 4 + q;
            float g = 0.f;
            if (m <= i) g = __expf(fminf(cuS[i] - cum, 0.f)) * dtm * graw[mt][q];
            Gb[i][m] = f2bf(g);
        }
    }
    // matmul2: inter tiles (it=w, pt=0..3)
    f32x4 acc[4];
    #pragma unroll
    for (int pt = 0; pt < 4; ++pt) {
        const short8 hfrag = *(const short8*)&Hs[pt * 16 + rowf][ko * 8];
        acc[pt] = __builtin_amdgcn_mfma_f32_16x16x32_bf16(cfrag, hfrag, (f32x4){0.f,0.f,0.f,0.f}, 0, 0, 0);
    }
    const float Dh = Ds[h];
    #pragma unroll
    for (int pt = 0; pt < 4; ++pt) {
        const int p = pt * 16 + rowf;
        const int xsw = (pt * 2 + (rowf >> 3)) & 7;
        #pragma unroll
        for (int q = 0; q < 4; ++q) {
            const int i = w * 16 + ko * 4 + q;
            acc[pt][q] = acc[pt][q] * Ei[i] + Dh * bf2f(Xb[p][(((i >> 3) ^ xsw) << 3) + (i & 7)]);
        }
    }
    // matmul3: acc += G·X  (wave w reads only its own Gb rows)
    #pragma unroll
    for (int ks = 0; ks < 2; ++ks) {
        const short8 gfrag = *(const short8*)&Gb[w * 16 + rowf][ks * 32 + ko * 8];
        #pragma unroll
        for (int pt = 0; pt < 4; ++pt) {
            const int xsw = (pt * 2 + (rowf >> 3)) & 7;
            const short8 xfrag = *(const short8*)&Xb[pt * 16 + rowf][((ks * 4 + ko) ^ xsw) << 3];
            acc[pt] = __builtin_amdgcn_mfma_f32_16x16x32_bf16(gfrag, xfrag, acc[pt], 0, 0, 0);
        }
    }
    // epilogue: direct bf16 store (exactly one writer per element per direction)
    unsigned short* yk = (k == 0) ? y0 : y1;
    #pragma unroll
    for (int pt = 0; pt < 4; ++pt) {
        const int p = pt * 16 + rowf;
        #pragma unroll
        for (int q = 0; q < 4; ++q) {
            const int i = w * 16 + ko * 4 + q;
            const int pos = (k == 0) ? (c * QC + i) : (i * QC + c);
            yk[(((size_t)b << 12) + pos) * INNER + dch0 + p] = f2bf(acc[pt][q]);
        }
    }
}

__global__ __launch_bounds__(256)
void report_ws_kernel(float* __restrict__ out, int n, float val)
{
    const int e = blockIdx.x * 256 + threadIdx.x;
    if (e < n) out[e] = val;
}

// ---------------------------------------------------------------------------
extern "C" void kernel_launch(void* const* d_in, const int* in_sizes, int n_in,
                              void* d_out, int out_size, void* d_ws, size_t ws_size,
                              hipStream_t stream)
{
    const float* x          = (const float*)d_in[0];
    const float* W_in       = (const float*)d_in[1];
    const float* conv_w     = (const float*)d_in[2];
    const float* conv_b     = (const float*)d_in[3];
    const float* xpw        = (const float*)d_in[4];
    const float* A_logs     = (const float*)d_in[5];
    const float* Ds         = (const float*)d_in[6];
    const float* dt_bias    = (const float*)d_in[7];
    const float* init_states= (const float*)d_in[8];
    const float* W_out      = (const float*)d_in[9];
    const float* W1         = (const float*)d_in[10];
    const float* b1         = (const float*)d_in[11];
    const float* W2         = (const float*)d_in[12];
    const float* b2         = (const float*)d_in[13];
    float* out = (float*)d_out;

    if (ws_size < (size_t)WS_REQ) {
        const float mib = (float)((double)ws_size / 1048576.0);
        report_ws_kernel<<<(out_size + 255) / 256, 256, 0, stream>>>(out, out_size, mib);
        return;
    }

    char* ws = (char*)d_ws;
    unsigned short* xlz   = (unsigned short*)(ws + WS_XLZ);
    unsigned short* xc_bf = (unsigned short*)(ws + WS_XC);
    unsigned short* y1    = (unsigned short*)(ws + WS_Y1);
    unsigned short* BCbf  = (unsigned short*)(ws + WS_BCBF);
    float* dtraw = (float*)(ws + WS_DTRAW);
    float* cumend= (float*)(ws + WS_CUME);
    unsigned short* SHb   = (unsigned short*)(ws + WS_SHB);
    unsigned short* y0    = (unsigned short*)(ws + WS_Y0);
    unsigned short* x_bf  = (unsigned short*)(ws + WS_XBF);
    unsigned short* Winb  = (unsigned short*)(ws + WS_WINB);
    unsigned short* wpadb = (unsigned short*)(ws + WS_WPADB);
    unsigned short* Woutb = (unsigned short*)(ws + WS_WOUTB);
    unsigned short* W1b   = (unsigned short*)(ws + WS_W1B);
    unsigned short* W2b   = (unsigned short*)(ws + WS_W2B);
    unsigned short* out_bf = (unsigned short*)(ws + WS_BCBF); // overlay: BCbf dead after intra
    unsigned short* h1_bf  = (unsigned short*)(ws + WS_XLZ);  // overlay: xlz dead after out_proj

    const int M = BB * LL;  // 32768

    // 0) all conversions in one launch (x + weights)
    cvt_all_kernel<<<(6979584 + 255) / 256, 256, 0, stream>>>(x, W_in, W1, xpw, W_out, W2,
                                                              x_bf, Winb, W1b, wpadb, Woutb, W2b);

    // 1) xlz = bf16( x @ W_in^T )
    gemm_bf16<4,0,0><<<dim3(M/128, HID/128), 256, 0, stream>>>(x_bf, Winb, nullptr, nullptr, nullptr, xlz,
                                                               nullptr, nullptr, nullptr, CIN, HID, HID);

    // 2) depthwise conv + bias + SiLU -> xc_bf
    conv_dw_kernel<<<196608 / 256, 256, 0, stream>>>(xlz, conv_w, conv_b, xc_bf);

    // 3) BCdt projection: both directions in ONE dispatch (512 blocks)
    gemm_bcdt<<<dim3(M/128, 2), 256, 0, stream>>>(xc_bf, wpadb, dtraw, BCbf);

    // 4) chunked scan (dt prefix computed in-block; no dtcums launch)
    chunk_state_kernel<<<dim3(NC, NHEADS, BB), 256, 0, stream>>>(xc_bf, BCbf, dtraw, dt_bias, A_logs,
                                                                 cumend, SHb);
    state_scan_kernel<<<BB * NHEADS * 8, 64, 0, stream>>>(SHb, cumend, init_states);
    intra_kernel<<<dim3(NC, NHEADS, BB), 256, 0, stream>>>(xc_bf, BCbf, dtraw, dt_bias, A_logs,
                                                           SHb, Ds, y0, y1);

    // 5) out = x + ((y0+y1)*silu(z)) @ W_out^T   (gate fused into A staging)
    gemm_bf16<3,0,2><<<dim3(M/128, 2), 256, 0, stream>>>(nullptr, Woutb, nullptr, x, out, out_bf,
                                                         y0, y1, xlz, INNER, CIN, CIN);

    // 6) MLP: h1_bf = bf16(silu(out @ W1^T + b1))
    gemm_bf16<1,0,0><<<dim3(M/128, HID/128), 256, 0, stream>>>(out_bf, W1b, b1, nullptr, nullptr, h1_bf,
                                                               nullptr, nullptr, nullptr, CIN, HID, HID);

    // 6b) out += h1 @ W2^T + b2
    gemm_bf16<2,0,0><<<dim3(M/128, 2), 256, 0, stream>>>(h1_bf, W2b, b2, out, out, nullptr,
                                                         nullptr, nullptr, nullptr, HID, CIN, CIN);
}

// Round 22
// 220.784 us; speedup vs baseline: 1.0093x; 1.0093x over previous
//
#include <hip/hip_runtime.h>
#include <math.h>

#define BB 8
#define HH 64
#define WW 64
#define CIN 192
#define INNER 384
#define LL 4096          // HH*WW
#define NSTATE 32
#define PDIM 64
#define NHK 6            // INNER/PDIM
#define NHEADS 12        // 2*NHK
#define HID 768
#define CPROJ 70         // 2*NSTATE + NHK
#define QC 64            // chunk length
#define NC 64            // LL/QC chunks

// workspace layout (bytes)
#define WS_XLZ   0u                   // bf16 xlz (B,L,768) 50331648 ; h1_bf overlay after out_proj
#define WS_XC    50331648u            // bf16 xc (B,L,384) 25165824
#define WS_Y1    75497472u            // bf16 y1 (B,L,384) 25165824
#define WS_BCBF  100663296u           // bf16 BCbf (B,L,2,64) 8388608 ; out_bf overlay after intra
#define WS_DTRAW 109051904u           // f32 dtraw (B,L,2,6) 1572864 (dead after dtcums)
#define WS_DTV   119013376u           // (B,L,12) f32 1572864
#define WS_CUMS  120586240u           // (B,L,12) f32 1572864
#define WS_SHB   122159104u           // bf16 SH (B,NH,NC,P,N) 25165824
#define WS_Y0    147324928u           // bf16 y0 (B,L,384) 25165824
#define WS_XBF   172490752u           // bf16 x_bf (M,192) 12582912 (dead after in_proj)
#define WS_WINB  185073664u           // W_in bf16 768x192      294912
#define WS_WPADB 185368576u           // xpw padded bf16 2x128x384 196608
#define WS_WOUTB 185565184u           // W_out padded bf16 256x384 196608
#define WS_W1B   185761792u           // W1 bf16 768x192        294912
#define WS_W2B   186056704u           // W2 padded bf16 256x768 393216
#define WS_REQ   186449920u

typedef __attribute__((ext_vector_type(8))) short short8;
typedef __attribute__((ext_vector_type(4))) float f32x4;

__device__ __forceinline__ float silu_f(float x) { return x / (1.f + __expf(-x)); }

__device__ __forceinline__ unsigned short f2bf(float f) {
    unsigned u = __float_as_uint(f);
    u += 0x7fffu + ((u >> 16) & 1u);
    return (unsigned short)(u >> 16);
}
__device__ __forceinline__ float bf2f(unsigned short u) {
    return __uint_as_float(((unsigned)u) << 16);
}

// ---------------------------------------------------------------------------
// A-fragment loader.  AMODE 0: bf16.  2: gated (y0+y1)*silu(z).
// ---------------------------------------------------------------------------
template<int AMODE>
__device__ __forceinline__ short8 load_a(const void* A, const unsigned short* Ay0,
                                         const unsigned short* Ay1, const unsigned short* Az,
                                         int row, int col, int Kd)
{
    if constexpr (AMODE == 0) {
        return *(const short8*)((const unsigned short*)A + (size_t)row * Kd + col);
    } else {
        const size_t yo = (size_t)row * INNER + col;
        const uint4 a  = *(const uint4*)(Ay0 + yo);
        const uint4 bv = *(const uint4*)(Ay1 + yo);
        const uint4 zv = *(const uint4*)(Az + (size_t)row * 768 + INNER + col);
        const unsigned ua[4]={a.x,a.y,a.z,a.w}, ub[4]={bv.x,bv.y,bv.z,bv.w}, uz[4]={zv.x,zv.y,zv.z,zv.w};
        short8 r;
        #pragma unroll
        for (int w2 = 0; w2 < 4; ++w2) {
            const float ylo = __uint_as_float(ua[w2] << 16) + __uint_as_float(ub[w2] << 16);
            const float yhi = __uint_as_float(ua[w2] & 0xffff0000u) + __uint_as_float(ub[w2] & 0xffff0000u);
            const float zlo = __uint_as_float(uz[w2] << 16);
            const float zhi = __uint_as_float(uz[w2] & 0xffff0000u);
            r[2*w2+0] = (short)f2bf(ylo * silu_f(zlo));
            r[2*w2+1] = (short)f2bf(yhi * silu_f(zhi));
        }
        return r;
    }
}

// ---------------------------------------------------------------------------
// bf16 MFMA GEMM: C[m,n] = sum_k A[m,k]*Wt[n,k].  128x128 tile, BK=64.
// EPI: 0 Cf=acc; 1 Cb=bf16(silu(acc+bias)); 2 Cf=acc+bias+res; 3 Cf=acc+res & Cb;
//      4 Cb=bf16(acc).
// ---------------------------------------------------------------------------
template<int EPI, int TRANSA, int AMODE>
__global__ __launch_bounds__(256)
void gemm_bf16(const void* __restrict__ A, const unsigned short* __restrict__ Wt,
               const float* __restrict__ bias, const float* __restrict__ res,
               float* __restrict__ Cf, unsigned short* __restrict__ Cb,
               const unsigned short* __restrict__ Ay0, const unsigned short* __restrict__ Ay1,
               const unsigned short* __restrict__ Az,
               int Kd, int ldc, int nmax)
{
    __shared__ __align__(16) short Als[128 * 64];
    __shared__ __align__(16) short Bls[128 * 64];
    const int tid = threadIdx.x;
    const int m0 = blockIdx.x * 128;
    const int n0 = blockIdx.y * 128;
    const int lane = tid & 63;
    const int wv = tid >> 6;
    const int wm = (wv >> 1) << 6;
    const int wn = (wv & 1) << 6;

    int am[4], ac[4];
    const unsigned short* gB[4];
    int lw[4];
    #pragma unroll
    for (int c = 0; c < 4; ++c) {
        const int idx = c * 256 + tid;
        const int row = idx >> 3;
        const int kb  = idx & 7;
        const int sb  = kb ^ (row & 7);
        lw[c] = row * 64 + sb * 8;
        int arow;
        const int mm = m0 + row;
        if (TRANSA) {
            const int bq = mm >> 12, lq = mm & 4095;
            arow = (bq << 12) + (((lq & 63) << 6) + (lq >> 6));
        } else {
            arow = mm;
        }
        am[c] = arow;
        ac[c] = kb * 8;
        gB[c] = Wt + (size_t)(n0 + row) * Kd + kb * 8;
    }

    f32x4 acc[4][4];
    #pragma unroll
    for (int i = 0; i < 4; ++i)
        #pragma unroll
        for (int j = 0; j < 4; ++j) acc[i][j] = (f32x4){0.f, 0.f, 0.f, 0.f};

    const int NT = Kd >> 6;
    short8 pA[4], pB[4];
    #pragma unroll
    for (int c = 0; c < 4; ++c) {
        pA[c] = load_a<AMODE>(A, Ay0, Ay1, Az, am[c], ac[c], Kd);
        pB[c] = *(const short8*)(gB[c]);
    }
    for (int kt = 0; kt < NT; ++kt) {
        __syncthreads();
        #pragma unroll
        for (int c = 0; c < 4; ++c) {
            *(short8*)&Als[lw[c]] = pA[c];
            *(short8*)&Bls[lw[c]] = pB[c];
        }
        __syncthreads();
        if (kt + 1 < NT) {
            #pragma unroll
            for (int c = 0; c < 4; ++c) {
                pA[c] = load_a<AMODE>(A, Ay0, Ay1, Az, am[c], ac[c] + (kt + 1) * 64, Kd);
                pB[c] = *(const short8*)(gB[c] + (kt + 1) * 64);
            }
        }
        #pragma unroll
        for (int ks = 0; ks < 2; ++ks) {
            short8 af[4], bfr[4];
            #pragma unroll
            for (int r = 0; r < 4; ++r) {
                const int rowa = wm + r * 16 + (lane & 15);
                const int rowb = wn + r * 16 + (lane & 15);
                const int kb = ks * 4 + (lane >> 4);
                af[r]  = *(const short8*)&Als[rowa * 64 + ((kb ^ (rowa & 7)) << 3)];
                bfr[r] = *(const short8*)&Bls[rowb * 64 + ((kb ^ (rowb & 7)) << 3)];
            }
            #pragma unroll
            for (int mr = 0; mr < 4; ++mr)
                #pragma unroll
                for (int nr = 0; nr < 4; ++nr)
                    acc[mr][nr] = __builtin_amdgcn_mfma_f32_16x16x32_bf16(af[mr], bfr[nr], acc[mr][nr], 0, 0, 0);
        }
    }
    #pragma unroll
    for (int mr = 0; mr < 4; ++mr) {
        #pragma unroll
        for (int nr = 0; nr < 4; ++nr) {
            const int n = n0 + wn + nr * 16 + (lane & 15);
            if (n >= nmax) continue;
            const int mb = m0 + wm + mr * 16 + ((lane >> 4) << 2);
            #pragma unroll
            for (int q = 0; q < 4; ++q) {
                const size_t off = (size_t)(mb + q) * ldc + n;
                float v = acc[mr][nr][q];
                if (EPI == 0) { Cf[off] = v; }
                else if (EPI == 1) { v = silu_f(v + bias[n]); Cb[off] = f2bf(v); }
                else if (EPI == 2) { v += bias[n] + res[off]; Cf[off] = v; }
                else if (EPI == 3) { v += res[off]; Cf[off] = v; Cb[off] = f2bf(v); }
                else if (EPI == 4) { Cb[off] = f2bf(v); }
            }
        }
    }
}

// ---------------------------------------------------------------------------
// Merged BCdt projection: both scan directions in one dispatch.
// grid (M/128, 2); blockIdx.y = k.
// ---------------------------------------------------------------------------
__global__ __launch_bounds__(256)
void gemm_bcdt(const unsigned short* __restrict__ A, const unsigned short* __restrict__ wpadb,
               float* __restrict__ dtraw, unsigned short* __restrict__ BCbf)
{
    __shared__ __align__(16) short Als[128 * 64];
    __shared__ __align__(16) short Bls[128 * 64];
    const int tid = threadIdx.x;
    const int m0 = blockIdx.x * 128;
    const int kk = blockIdx.y;
    const int lane = tid & 63;
    const int wv = tid >> 6;
    const int wm = (wv >> 1) << 6;
    const int wn = (wv & 1) << 6;
    const int Kd = INNER;
    const unsigned short* Wt = wpadb + (size_t)kk * 128 * INNER;

    int am[4], ac[4];
    const unsigned short* gB[4];
    int lw[4];
    #pragma unroll
    for (int c = 0; c < 4; ++c) {
        const int idx = c * 256 + tid;
        const int row = idx >> 3;
        const int kb  = idx & 7;
        const int sb  = kb ^ (row & 7);
        lw[c] = row * 64 + sb * 8;
        const int mm = m0 + row;
        int arow;
        if (kk) {
            const int bq = mm >> 12, lq = mm & 4095;
            arow = (bq << 12) + (((lq & 63) << 6) + (lq >> 6));
        } else {
            arow = mm;
        }
        am[c] = arow;
        ac[c] = kb * 8;
        gB[c] = Wt + (size_t)row * Kd + kb * 8;
    }

    f32x4 acc[4][4];
    #pragma unroll
    for (int i = 0; i < 4; ++i)
        #pragma unroll
        for (int j = 0; j < 4; ++j) acc[i][j] = (f32x4){0.f, 0.f, 0.f, 0.f};

    short8 pA[4], pB[4];
    #pragma unroll
    for (int c = 0; c < 4; ++c) {
        pA[c] = *(const short8*)(A + (size_t)am[c] * Kd + ac[c]);
        pB[c] = *(const short8*)(gB[c]);
    }
    for (int kt = 0; kt < 6; ++kt) {
        __syncthreads();
        #pragma unroll
        for (int c = 0; c < 4; ++c) {
            *(short8*)&Als[lw[c]] = pA[c];
            *(short8*)&Bls[lw[c]] = pB[c];
        }
        __syncthreads();
        if (kt + 1 < 6) {
            #pragma unroll
            for (int c = 0; c < 4; ++c) {
                pA[c] = *(const short8*)(A + (size_t)am[c] * Kd + ac[c] + (kt + 1) * 64);
                pB[c] = *(const short8*)(gB[c] + (kt + 1) * 64);
            }
        }
        #pragma unroll
        for (int ks = 0; ks < 2; ++ks) {
            short8 af[4], bfr[4];
            #pragma unroll
            for (int r = 0; r < 4; ++r) {
                const int rowa = wm + r * 16 + (lane & 15);
                const int rowb = wn + r * 16 + (lane & 15);
                const int kb = ks * 4 + (lane >> 4);
                af[r]  = *(const short8*)&Als[rowa * 64 + ((kb ^ (rowa & 7)) << 3)];
                bfr[r] = *(const short8*)&Bls[rowb * 64 + ((kb ^ (rowb & 7)) << 3)];
            }
            #pragma unroll
            for (int mr = 0; mr < 4; ++mr)
                #pragma unroll
                for (int nr = 0; nr < 4; ++nr)
                    acc[mr][nr] = __builtin_amdgcn_mfma_f32_16x16x32_bf16(af[mr], bfr[nr], acc[mr][nr], 0, 0, 0);
        }
    }
    float* Cf = dtraw + 6 * kk;
    unsigned short* Cb = BCbf + 64 * kk;
    #pragma unroll
    for (int mr = 0; mr < 4; ++mr) {
        #pragma unroll
        for (int nr = 0; nr < 4; ++nr) {
            const int n = wn + nr * 16 + (lane & 15);
            if (n >= CPROJ) continue;
            const int mb = m0 + wm + mr * 16 + ((lane >> 4) << 2);
            #pragma unroll
            for (int q = 0; q < 4; ++q) {
                const float v = acc[mr][nr][q];
                if (n < 64) Cb[(size_t)(mb + q) * 128 + n] = f2bf(v);
                else        Cf[(size_t)(mb + q) * 12 + (n - 64)] = v;
            }
        }
    }
}

// ---------------------------------------------------------------------------
// All conversions in one launch: x (6291456) then weights (688128).
// ---------------------------------------------------------------------------
__global__ __launch_bounds__(256)
void cvt_all_kernel(const float* __restrict__ x, const float* __restrict__ W_in,
                    const float* __restrict__ W1, const float* __restrict__ xpw,
                    const float* __restrict__ W_out, const float* __restrict__ W2,
                    unsigned short* __restrict__ x_bf,
                    unsigned short* __restrict__ Winb, unsigned short* __restrict__ W1b,
                    unsigned short* __restrict__ wpadb, unsigned short* __restrict__ Woutb,
                    unsigned short* __restrict__ W2b)
{
    int i = blockIdx.x * 256 + threadIdx.x;
    if (i < 6291456) { x_bf[i] = f2bf(x[i]); return; }
    i -= 6291456;
    if (i < 147456) { Winb[i] = f2bf(W_in[i]); return; }
    i -= 147456;
    if (i < 147456) { W1b[i] = f2bf(W1[i]); return; }
    i -= 147456;
    if (i < 98304) {
        const int d = i % 384;
        const int rr = (i / 384) & 127;
        const int k = i / 49152;
        wpadb[i] = (rr < CPROJ) ? f2bf(xpw[((size_t)k * CPROJ + rr) * 384 + d]) : (unsigned short)0;
        return;
    }
    i -= 98304;
    if (i < 98304) {
        const int rr = i / 384;
        Woutb[i] = (rr < CIN) ? f2bf(W_out[i]) : (unsigned short)0;
        return;
    }
    i -= 98304;
    if (i < 196608) {
        const int rr = i / 768;
        W2b[i] = (rr < CIN) ? f2bf(W2[i]) : (unsigned short)0;
    }
}

// ---------------------------------------------------------------------------
// Depthwise 3x3 conv + bias + SiLU, rolling-row (8 rows/thread, 8 ch/thread).
// ---------------------------------------------------------------------------
__global__ __launch_bounds__(256)
void conv_dw_kernel(const unsigned short* __restrict__ xlz, const float* __restrict__ cw,
                    const float* __restrict__ cb, unsigned short* __restrict__ xcbf)
{
    const int t = blockIdx.x * 256 + threadIdx.x;   // < 196608
    const int dv = t % 48;
    int r = t / 48;
    const int j  = r & 63;  r >>= 6;
    const int ib = r & 7;   r >>= 3;
    const int b  = r;
    const int d0 = dv * 8;
    const int i0 = ib * 8;

    float wreg[72];
    {
        const float4* w4 = (const float4*)(cw + d0 * 9);
        #pragma unroll
        for (int u = 0; u < 18; ++u) {
            const float4 v = w4[u];
            wreg[4*u+0]=v.x; wreg[4*u+1]=v.y; wreg[4*u+2]=v.z; wreg[4*u+3]=v.w;
        }
    }
    float bias[8];
    {
        const float4 b0 = *(const float4*)(cb + d0);
        const float4 b1 = *(const float4*)(cb + d0 + 4);
        bias[0]=b0.x; bias[1]=b0.y; bias[2]=b0.z; bias[3]=b0.w;
        bias[4]=b1.x; bias[5]=b1.y; bias[6]=b1.z; bias[7]=b1.w;
    }

    const unsigned short* base = xlz + ((size_t)b << 12) * 768 + d0;
    const int jok[3] = { (j - 1 >= 0), 1, (j + 1 < WW) };

    unsigned rm[3][4], r0[3][4], rp[3][4];
    #pragma unroll
    for (int cj = 0; cj < 3; ++cj) {
        uint4 vm = make_uint4(0,0,0,0), v0 = make_uint4(0,0,0,0);
        if (jok[cj]) {
            if (i0 - 1 >= 0) vm = *(const uint4*)(base + (size_t)((i0-1) * 64 + j - 1 + cj) * 768);
            v0 = *(const uint4*)(base + (size_t)(i0 * 64 + j - 1 + cj) * 768);
        }
        rm[cj][0]=vm.x; rm[cj][1]=vm.y; rm[cj][2]=vm.z; rm[cj][3]=vm.w;
        r0[cj][0]=v0.x; r0[cj][1]=v0.y; r0[cj][2]=v0.z; r0[cj][3]=v0.w;
    }

    #pragma unroll
    for (int ii = 0; ii < 8; ++ii) {
        const int i = i0 + ii;
        #pragma unroll
        for (int cj = 0; cj < 3; ++cj) {
            uint4 vp = make_uint4(0,0,0,0);
            if (jok[cj] && (i + 1 < HH))
                vp = *(const uint4*)(base + (size_t)((i+1) * 64 + j - 1 + cj) * 768);
            rp[cj][0]=vp.x; rp[cj][1]=vp.y; rp[cj][2]=vp.z; rp[cj][3]=vp.w;
        }
        float acc[8];
        #pragma unroll
        for (int ch = 0; ch < 8; ++ch) acc[ch] = bias[ch];
        #pragma unroll
        for (int cj = 0; cj < 3; ++cj) {
            #pragma unroll
            for (int w2 = 0; w2 < 4; ++w2) {
                acc[2*w2+0] = fmaf(__uint_as_float(rm[cj][w2] << 16),        wreg[(2*w2+0)*9 + cj],     acc[2*w2+0]);
                acc[2*w2+1] = fmaf(__uint_as_float(rm[cj][w2] & 0xffff0000u), wreg[(2*w2+1)*9 + cj],     acc[2*w2+1]);
                acc[2*w2+0] = fmaf(__uint_as_float(r0[cj][w2] << 16),        wreg[(2*w2+0)*9 + 3 + cj], acc[2*w2+0]);
                acc[2*w2+1] = fmaf(__uint_as_float(r0[cj][w2] & 0xffff0000u), wreg[(2*w2+1)*9 + 3 + cj], acc[2*w2+1]);
                acc[2*w2+0] = fmaf(__uint_as_float(rp[cj][w2] << 16),        wreg[(2*w2+0)*9 + 6 + cj], acc[2*w2+0]);
                acc[2*w2+1] = fmaf(__uint_as_float(rp[cj][w2] & 0xffff0000u), wreg[(2*w2+1)*9 + 6 + cj], acc[2*w2+1]);
            }
        }
        unsigned o[4];
        #pragma unroll
        for (int w2 = 0; w2 < 4; ++w2) {
            const unsigned lo = f2bf(silu_f(acc[2*w2+0]));
            const unsigned hi = f2bf(silu_f(acc[2*w2+1]));
            o[w2] = lo | (hi << 16);
        }
        *(uint4*)(xcbf + ((size_t)(b << 12) + (size_t)(i * 64 + j)) * INNER + d0) =
            make_uint4(o[0], o[1], o[2], o[3]);
        #pragma unroll
        for (int cj = 0; cj < 3; ++cj)
            #pragma unroll
            for (int w2 = 0; w2 < 4; ++w2) {
                rm[cj][w2] = r0[cj][w2];
                r0[cj][w2] = rp[cj][w2];
            }
    }
}

// ---------------------------------------------------------------------------
// dtv = softplus(dtraw + dt_bias[h]); cums = per-chunk inclusive prefix sum
// ---------------------------------------------------------------------------
__global__ __launch_bounds__(256)
void dtcums_kernel(const float* __restrict__ dtraw, const float* __restrict__ dt_bias,
                   const float* __restrict__ A_logs,
                   float* __restrict__ dtv, float* __restrict__ cums)
{
    const int w = blockIdx.x * 4 + (threadIdx.x >> 6);
    const int lane = threadIdx.x & 63;
    const int b = w / (NHEADS * NC);
    const int rem = w - b * (NHEADS * NC);
    const int h = rem / NC;
    const int c = rem - h * NC;
    const int k = h / NHK;
    const int hq = h - k * NHK;
    const int l = c * QC + lane;
    const float dtr = dtraw[(((size_t)b * LL + l) * 2 + k) * 6 + hq];
    const float xx = dtr + dt_bias[h];
    const float sp = (xx > 20.f) ? xx : log1pf(expf(xx));
    float s = -expf(A_logs[h]) * sp;
    #pragma unroll
    for (int d = 1; d < 64; d <<= 1) {
        const float o = __shfl_up(s, d);
        if (lane >= d) s += o;
    }
    dtv[((size_t)b * LL + l) * NHEADS + h] = sp;
    cums[((size_t)b * LL + l) * NHEADS + h] = s;
}

// ---------------------------------------------------------------------------
// Chunk states via bf16 MFMA: S_c[p,n] = sum_m (rs[m]*x[m][p]) * B[m][n]
// Xb/Bsc column-blocks XOR-swizzled by (row>>3) for conflict-free staging.
// ---------------------------------------------------------------------------
__global__ __launch_bounds__(256)
void chunk_state_kernel(const unsigned short* __restrict__ xcbf, const unsigned short* __restrict__ BCbf,
                        const float* __restrict__ dtv, const float* __restrict__ cums,
                        unsigned short* __restrict__ SHb)
{
    __shared__ __align__(16) unsigned short Xb[PDIM][72];    // [p][m^]  (X^T, swizzled blocks)
    __shared__ __align__(16) unsigned short Bsc[NSTATE][72]; // [n][m^]  (rs[m]*B^T, swizzled)
    __shared__ float cuS[QC], rs[QC];
    const int c = blockIdx.x, h = blockIdx.y, b = blockIdx.z;
    const int k = h / NHK;
    const int dch0 = (h - k * NHK) * PDIM;
    const int tid = threadIdx.x;
    const int lane = tid & 63;
    const int w = tid >> 6;

    #pragma unroll
    for (int r2 = 0; r2 < 2; ++r2) {
        const int idx = tid + r2 * 256;
        const int m = idx >> 3, pg = idx & 7;
        const int pos = (k == 0) ? (c * QC + m) : (m * QC + c);
        const uint4 v = *(const uint4*)(xcbf + (((size_t)b << 12) + pos) * INNER + dch0 + pg * 8);
        const unsigned ua[4] = {v.x, v.y, v.z, v.w};
        const int mcol = (((m >> 3) ^ pg) << 3) + (m & 7);   // (p>>3)&7 == pg
        #pragma unroll
        for (int e2 = 0; e2 < 4; ++e2) {
            Xb[pg * 8 + 2*e2 + 0][mcol] = (unsigned short)(ua[e2] & 0xffffu);
            Xb[pg * 8 + 2*e2 + 1][mcol] = (unsigned short)(ua[e2] >> 16);
        }
    }
    if (tid < QC)
        cuS[tid] = cums[((size_t)b * LL + c * QC + tid) * NHEADS + h];
    __syncthreads();
    if (tid < QC)
        rs[tid] = dtv[((size_t)b * LL + c * QC + tid) * NHEADS + h] * __expf(cuS[QC-1] - cuS[tid]);
    __syncthreads();
    #pragma unroll
    for (int r = 0; r < 8; ++r) {
        const int idx = tid + r * 256;
        const int m = idx >> 5, n = idx & 31;
        Bsc[n][(((m >> 3) ^ (n >> 3)) << 3) + (m & 7)] =
            f2bf(rs[m] * bf2f(BCbf[(((size_t)b * LL + c * QC + m) * 2 + k) * 64 + n]));
    }
    __syncthreads();

    const int rowf = lane & 15;
    const int ko   = lane >> 4;
    const int xsw = (w * 2 + (rowf >> 3)) & 7;   // (row>>3)&7 for row = w*16+rowf
    f32x4 acc[2] = {{0.f,0.f,0.f,0.f},{0.f,0.f,0.f,0.f}};
    #pragma unroll
    for (int ks = 0; ks < 2; ++ks) {
        const short8 af = *(const short8*)&Xb[w * 16 + rowf][((ks * 4 + ko) ^ xsw) << 3];
        #pragma unroll
        for (int nt = 0; nt < 2; ++nt) {
            const int bsw = (nt * 2 + (rowf >> 3)) & 7;
            const short8 bfr = *(const short8*)&Bsc[nt * 16 + rowf][((ks * 4 + ko) ^ bsw) << 3];
            acc[nt] = __builtin_amdgcn_mfma_f32_16x16x32_bf16(af, bfr, acc[nt], 0, 0, 0);
        }
    }
    unsigned short* base = SHb + ((((size_t)b * NHEADS + h) * NC + c) * PDIM) * NSTATE;
    #pragma unroll
    for (int nt = 0; nt < 2; ++nt) {
        #pragma unroll
        for (int q = 0; q < 4; ++q) {
            const int p = w * 16 + ko * 4 + q;
            base[p * NSTATE + nt * 16 + rowf] = f2bf(acc[nt][q]);
        }
    }
}

// ---------------------------------------------------------------------------
// Sequential scan over chunks (in place, bf16 slots, f32 running state).
// 768 blocks x 64 threads, 4 elems (8B)/thread; next-slot prefetch breaks
// the global-load latency chain.
// ---------------------------------------------------------------------------
__global__ __launch_bounds__(64)
void state_scan_kernel(unsigned short* __restrict__ SHb, const float* __restrict__ cums,
                       const float* __restrict__ init_states)
{
    __shared__ float decays[NC];
    const int g = blockIdx.x;
    const int bh = g >> 3;
    const int oct = g & 7;
    const int b = bh / NHEADS;
    const int h = bh % NHEADS;
    const int tid = threadIdx.x;
    decays[tid] = __expf(cums[((size_t)b * LL + tid * QC + QC - 1) * NHEADS + h]);
    __syncthreads();
    const int p  = oct * 8 + (tid >> 3);
    const int nb = (tid & 7) * 4;
    float hs[4];
    {
        const float* is = init_states + ((size_t)h * PDIM + p) * NSTATE + nb;
        hs[0]=is[0]; hs[1]=is[1]; hs[2]=is[2]; hs[3]=is[3];
    }
    unsigned short* base = SHb + (((size_t)b * NHEADS + h) * NC) * (PDIM * NSTATE) + p * NSTATE + nb;
    uint2 sv = *(const uint2*)base;
    for (int c = 0; c < NC; ++c) {
        unsigned short* slot = base + (size_t)c * (PDIM * NSTATE);
        uint2 nx = make_uint2(0u, 0u);
        if (c + 1 < NC) nx = *(const uint2*)(slot + PDIM * NSTATE);
        const unsigned o0 = (unsigned)f2bf(hs[0]) | ((unsigned)f2bf(hs[1]) << 16);
        const unsigned o1 = (unsigned)f2bf(hs[2]) | ((unsigned)f2bf(hs[3]) << 16);
        *(uint2*)slot = make_uint2(o0, o1);
        const float dc = decays[c];
        hs[0] = fmaf(dc, hs[0], __uint_as_float(sv.x << 16));
        hs[1] = fmaf(dc, hs[1], __uint_as_float(sv.x & 0xffff0000u));
        hs[2] = fmaf(dc, hs[2], __uint_as_float(sv.y << 16));
        hs[3] = fmaf(dc, hs[3], __uint_as_float(sv.y & 0xffff0000u));
        sv = nx;
    }
}

// ---------------------------------------------------------------------------
// Intra-chunk + inter-chunk + D term via bf16 MFMA.  grid (NC, NHEADS, BB).
// Xb column-blocks XOR-swizzled by (row>>3) (conflict-free staging writes).
// ---------------------------------------------------------------------------
__global__ __launch_bounds__(256)
void intra_kernel(const unsigned short* __restrict__ xcbf, const unsigned short* __restrict__ BCbf,
                  const float* __restrict__ dtv, const float* __restrict__ cums,
                  const unsigned short* __restrict__ SHb, const float* __restrict__ Ds,
                  unsigned short* __restrict__ y0, unsigned short* __restrict__ y1)
{
    __shared__ __align__(16) unsigned short Bs[QC][40];    // [m][n]
    __shared__ __align__(16) unsigned short Cs[QC][40];    // [i][n]
    __shared__ __align__(16) unsigned short Hs[PDIM][40];  // [p][n]
    __shared__ __align__(16) unsigned short Xb[PDIM][72];  // [p][m^]  (X^T, swizzled)
    __shared__ __align__(16) unsigned short Gb[QC][72];    // [i][m]
    __shared__ float cuS[QC], dtS[QC], Ei[QC];
    const int c = blockIdx.x, h = blockIdx.y, b = blockIdx.z;
    const int k = h / NHK;
    const int dch0 = (h - k * NHK) * PDIM;
    const int tid = threadIdx.x;
    const int lane = tid & 63;
    const int w = tid >> 6;

    #pragma unroll
    for (int r2 = 0; r2 < 2; ++r2) {
        const int idx = tid + r2 * 256;
        const int m = idx >> 3, pg = idx & 7;
        const int pos = (k == 0) ? (c * QC + m) : (m * QC + c);
        const uint4 v = *(const uint4*)(xcbf + (((size_t)b << 12) + pos) * INNER + dch0 + pg * 8);
        const unsigned ua[4] = {v.x, v.y, v.z, v.w};
        const int mcol = (((m >> 3) ^ pg) << 3) + (m & 7);
        #pragma unroll
        for (int e2 = 0; e2 < 4; ++e2) {
            Xb[pg * 8 + 2*e2 + 0][mcol] = (unsigned short)(ua[e2] & 0xffffu);
            Xb[pg * 8 + 2*e2 + 1][mcol] = (unsigned short)(ua[e2] >> 16);
        }
    }
    // B/C: vector copy from BCbf (b,l,2,64)
    #pragma unroll
    for (int r = 0; r < 2; ++r) {
        const int idx = tid + r * 256;
        const int i = idx >> 3, ch = idx & 7;
        const uint4 v = *(const uint4*)(BCbf + (((size_t)b * LL + c * QC + i) * 2 + k) * 64 + ch * 8);
        if (ch < 4) *(uint4*)&Bs[i][ch * 8] = v;
        else        *(uint4*)&Cs[i][(ch - 4) * 8] = v;
    }
    // H: vector copy
    {
        const int p = tid >> 2, ch = tid & 3;
        *(uint4*)&Hs[p][ch * 8] =
            *(const uint4*)(SHb + ((((size_t)b * NHEADS + h) * NC + c) * PDIM + p) * NSTATE + ch * 8);
    }
    if (tid < QC) {
        const size_t o = ((size_t)b * LL + c * QC + tid) * NHEADS + h;
        const float cu = cums[o];
        cuS[tid] = cu;
        dtS[tid] = dtv[o];
        Ei[tid]  = __expf(cu);
    }
    __syncthreads();

    const int rowf = lane & 15;
    const int ko   = lane >> 4;
    const short8 cfrag = *(const short8*)&Cs[w * 16 + rowf][ko * 8];

    // matmul1: G_raw tiles (it=w, mt=0..3)
    f32x4 graw[4];
    #pragma unroll
    for (int mt = 0; mt < 4; ++mt) {
        const short8 bfrag = *(const short8*)&Bs[mt * 16 + rowf][ko * 8];
        graw[mt] = __builtin_amdgcn_mfma_f32_16x16x32_bf16(cfrag, bfrag, (f32x4){0.f,0.f,0.f,0.f}, 0, 0, 0);
    }
    #pragma unroll
    for (int mt = 0; mt < 4; ++mt) {
        const int m = mt * 16 + rowf;
        const float cum = cuS[m];
        const float dtm = dtS[m];
        #pragma unroll
        for (int q = 0; q < 4; ++q) {
            const int i = w * 16 + ko * 4 + q;
            float g = 0.f;
            if (m <= i) g = __expf(fminf(cuS[i] - cum, 0.f)) * dtm * graw[mt][q];
            Gb[i][m] = f2bf(g);
        }
    }
    // matmul2: inter tiles (it=w, pt=0..3)
    f32x4 acc[4];
    #pragma unroll
    for (int pt = 0; pt < 4; ++pt) {
        const short8 hfrag = *(const short8*)&Hs[pt * 16 + rowf][ko * 8];
        acc[pt] = __builtin_amdgcn_mfma_f32_16x16x32_bf16(cfrag, hfrag, (f32x4){0.f,0.f,0.f,0.f}, 0, 0, 0);
    }
    const float Dh = Ds[h];
    #pragma unroll
    for (int pt = 0; pt < 4; ++pt) {
        const int p = pt * 16 + rowf;
        const int xsw = (pt * 2 + (rowf >> 3)) & 7;
        #pragma unroll
        for (int q = 0; q < 4; ++q) {
            const int i = w * 16 + ko * 4 + q;
            acc[pt][q] = acc[pt][q] * Ei[i] + Dh * bf2f(Xb[p][(((i >> 3) ^ xsw) << 3) + (i & 7)]);
        }
    }
    // matmul3: acc += G·X  (wave w reads only its own Gb rows)
    #pragma unroll
    for (int ks = 0; ks < 2; ++ks) {
        const short8 gfrag = *(const short8*)&Gb[w * 16 + rowf][ks * 32 + ko * 8];
        #pragma unroll
        for (int pt = 0; pt < 4; ++pt) {
            const int xsw = (pt * 2 + (rowf >> 3)) & 7;
            const short8 xfrag = *(const short8*)&Xb[pt * 16 + rowf][((ks * 4 + ko) ^ xsw) << 3];
            acc[pt] = __builtin_amdgcn_mfma_f32_16x16x32_bf16(gfrag, xfrag, acc[pt], 0, 0, 0);
        }
    }
    // epilogue: direct bf16 store (exactly one writer per element per direction)
    unsigned short* yk = (k == 0) ? y0 : y1;
    #pragma unroll
    for (int pt = 0; pt < 4; ++pt) {
        const int p = pt * 16 + rowf;
        #pragma unroll
        for (int q = 0; q < 4; ++q) {
            const int i = w * 16 + ko * 4 + q;
            const int pos = (k == 0) ? (c * QC + i) : (i * QC + c);
            yk[(((size_t)b << 12) + pos) * INNER + dch0 + p] = f2bf(acc[pt][q]);
        }
    }
}

__global__ __launch_bounds__(256)
void report_ws_kernel(float* __restrict__ out, int n, float val)
{
    const int e = blockIdx.x * 256 + threadIdx.x;
    if (e < n) out[e] = val;
}

// ---------------------------------------------------------------------------
extern "C" void kernel_launch(void* const* d_in, const int* in_sizes, int n_in,
                              void* d_out, int out_size, void* d_ws, size_t ws_size,
                              hipStream_t stream)
{
    const float* x          = (const float*)d_in[0];
    const float* W_in       = (const float*)d_in[1];
    const float* conv_w     = (const float*)d_in[2];
    const float* conv_b     = (const float*)d_in[3];
    const float* xpw        = (const float*)d_in[4];
    const float* A_logs     = (const float*)d_in[5];
    const float* Ds         = (const float*)d_in[6];
    const float* dt_bias    = (const float*)d_in[7];
    const float* init_states= (const float*)d_in[8];
    const float* W_out      = (const float*)d_in[9];
    const float* W1         = (const float*)d_in[10];
    const float* b1         = (const float*)d_in[11];
    const float* W2         = (const float*)d_in[12];
    const float* b2         = (const float*)d_in[13];
    float* out = (float*)d_out;

    if (ws_size < (size_t)WS_REQ) {
        const float mib = (float)((double)ws_size / 1048576.0);
        report_ws_kernel<<<(out_size + 255) / 256, 256, 0, stream>>>(out, out_size, mib);
        return;
    }

    char* ws = (char*)d_ws;
    unsigned short* xlz   = (unsigned short*)(ws + WS_XLZ);
    unsigned short* xc_bf = (unsigned short*)(ws + WS_XC);
    unsigned short* y1    = (unsigned short*)(ws + WS_Y1);
    unsigned short* BCbf  = (unsigned short*)(ws + WS_BCBF);
    float* dtraw = (float*)(ws + WS_DTRAW);
    float* dtv   = (float*)(ws + WS_DTV);
    float* cums  = (float*)(ws + WS_CUMS);
    unsigned short* SHb   = (unsigned short*)(ws + WS_SHB);
    unsigned short* y0    = (unsigned short*)(ws + WS_Y0);
    unsigned short* x_bf  = (unsigned short*)(ws + WS_XBF);
    unsigned short* Winb  = (unsigned short*)(ws + WS_WINB);
    unsigned short* wpadb = (unsigned short*)(ws + WS_WPADB);
    unsigned short* Woutb = (unsigned short*)(ws + WS_WOUTB);
    unsigned short* W1b   = (unsigned short*)(ws + WS_W1B);
    unsigned short* W2b   = (unsigned short*)(ws + WS_W2B);
    unsigned short* out_bf = (unsigned short*)(ws + WS_BCBF); // overlay: BCbf dead after intra
    unsigned short* h1_bf  = (unsigned short*)(ws + WS_XLZ);  // overlay: xlz dead after out_proj

    const int M = BB * LL;  // 32768

    // 0) all conversions in one launch (x + weights)
    cvt_all_kernel<<<(6979584 + 255) / 256, 256, 0, stream>>>(x, W_in, W1, xpw, W_out, W2,
                                                              x_bf, Winb, W1b, wpadb, Woutb, W2b);

    // 1) xlz = bf16( x @ W_in^T )
    gemm_bf16<4,0,0><<<dim3(M/128, HID/128), 256, 0, stream>>>(x_bf, Winb, nullptr, nullptr, nullptr, xlz,
                                                               nullptr, nullptr, nullptr, CIN, HID, HID);

    // 2) depthwise conv + bias + SiLU -> xc_bf
    conv_dw_kernel<<<196608 / 256, 256, 0, stream>>>(xlz, conv_w, conv_b, xc_bf);

    // 3) BCdt projection: both directions in ONE dispatch (512 blocks)
    gemm_bcdt<<<dim3(M/128, 2), 256, 0, stream>>>(xc_bf, wpadb, dtraw, BCbf);

    // 3b) dt softplus + per-chunk cumsum
    dtcums_kernel<<<(BB * NHEADS * NC) / 4, 256, 0, stream>>>(dtraw, dt_bias, A_logs, dtv, cums);

    // 4) chunked scan (no memset, no atomics)
    chunk_state_kernel<<<dim3(NC, NHEADS, BB), 256, 0, stream>>>(xc_bf, BCbf, dtv, cums, SHb);
    state_scan_kernel<<<BB * NHEADS * 8, 64, 0, stream>>>(SHb, cums, init_states);
    intra_kernel<<<dim3(NC, NHEADS, BB), 256, 0, stream>>>(xc_bf, BCbf, dtv, cums, SHb, Ds, y0, y1);

    // 5) out = x + ((y0+y1)*silu(z)) @ W_out^T   (gate fused into A staging)
    gemm_bf16<3,0,2><<<dim3(M/128, 2), 256, 0, stream>>>(nullptr, Woutb, nullptr, x, out, out_bf,
                                                         y0, y1, xlz, INNER, CIN, CIN);

    // 6) MLP: h1_bf = bf16(silu(out @ W1^T + b1))
    gemm_bf16<1,0,0><<<dim3(M/128, HID/128), 256, 0, stream>>>(out_bf, W1b, b1, nullptr, nullptr, h1_bf,
                                                               nullptr, nullptr, nullptr, CIN, HID, HID);

    // 6b) out += h1 @ W2^T + b2
    gemm_bf16<2,0,0><<<dim3(M/128, 2), 256, 0, stream>>>(h1_bf, W2b, b2, out, out, nullptr,
                                                         nullptr, nullptr, nullptr, HID, CIN, CIN);
}